// Round 15
// baseline (60.755 us; speedup 1.0000x reference)
//
#include <hip/hip_runtime.h>

typedef float v4f __attribute__((ext_vector_type(4)));
typedef float v2f __attribute__((ext_vector_type(2)));

#define LOG2E   1.4426950408889634f
#define NLOG2E (-1.4426950408889634f)
#define C2L2E   2.8853900817779268f   // 2*log2(e)
#define NM2L2E (-2.8853900817779268f) // -2*log2(e)
#define LN2     0.6931471805599453f

__device__ __forceinline__ float fexp2(float x){ return __builtin_amdgcn_exp2f(x); }
__device__ __forceinline__ float flog2(float x){ return __builtin_amdgcn_logf(x); }
__device__ __forceinline__ float frcp (float x){ return __builtin_amdgcn_rcpf(x); }
__device__ __forceinline__ float hsum(v4f v){ return (v.x+v.y)+(v.z+v.w); }

// ---------------------------------------------------------------------------
// prep (R8-proven, 64-row tiles, 200 blocks):
//   bid 0..127  : EA/EB = exp2((x @ W1half (+b1)) * 2log2e)
//   bid 128..191: xpT = (x @ Wp)^T
//   bid 192..199: sq[row] = ||x_row||^2
// ---------------------------------------------------------------------------
__global__ __launch_bounds__(256) void prep_kernel(
    const float* __restrict__ x, const float* __restrict__ W1,
    const float* __restrict__ b1, const float* __restrict__ Wp,
    float* __restrict__ sq, float* __restrict__ Abuf,
    float* __restrict__ Bbuf, float* __restrict__ xpT)
{
  const int bid = blockIdx.x, t = threadIdx.x;
  if (bid >= 192) {                       // ---- sq ----
    int row = (bid - 192) * 256 + t;      // 0..2047
    const v4f* xv = (const v4f*)(x + row * 128);
    float s = 0.f;
#pragma unroll
    for (int q = 0; q < 32; q++) { v4f v = xv[q]; s += hsum(v * v); }
    sq[row] = s;
    return;
  }
  __shared__ v4f Xs[64 * 9];              // 64 rows x 8 f4, pad 9, slot-swizzled
  __shared__ v4f Ws[32 * 16];             // 32 dd  x 16 f4 (64 cols)
  const bool isAB = bid < 128;
  int it, ct;
  if (isAB) { it = bid >> 2; ct = bid & 3; }
  else      { int q = bid - 128; it = q >> 1; ct = q & 1; }
  const int row0 = it * 64;
  const int tx = t & 15, ty = t >> 4;
  const int r0 = ty * 4, c0 = tx * 4;
  v4f acc[4] = {};                        // acc[i] over 4 cols

  for (int dd0 = 0; dd0 < 128; dd0 += 32) {
    __syncthreads();
#pragma unroll
    for (int s2 = 0; s2 < 2; s2++) {      // stage X (coalesced), swizzled slot
      int idx = t + s2 * 256;
      int row = idx >> 3, k4 = idx & 7;
      v4f v = *(const v4f*)(x + (row0 + row) * 128 + dd0 + k4 * 4);
      Xs[row * 9 + ((k4 + (row >> 2)) & 7)] = v;
    }
#pragma unroll
    for (int s2 = 0; s2 < 2; s2++) {      // stage W (f4 along cols)
      int idx = t + s2 * 256;
      int dd = idx >> 4, cf4 = idx & 15;
      v4f v;
      if (isAB) {
        int cl = cf4 * 4; int half = cl >> 5; int k = cl & 31;
        v = *(const v4f*)(W1 + (ct * 256 + half * 128 + dd0 + dd) * 32 + k);
      } else {
        v = *(const v4f*)(Wp + (dd0 + dd) * 128 + ct * 64 + cf4 * 4);
      }
      Ws[dd * 16 + cf4] = v;
    }
    __syncthreads();
#pragma unroll
    for (int dd4 = 0; dd4 < 8; dd4++) {
      int sa = (dd4 + ty) & 7;
      v4f a0 = Xs[(r0 + 0) * 9 + sa], a1 = Xs[(r0 + 1) * 9 + sa];
      v4f a2 = Xs[(r0 + 2) * 9 + sa], a3 = Xs[(r0 + 3) * 9 + sa];
#pragma unroll
      for (int u = 0; u < 4; u++) {
        v4f bv = Ws[(dd4 * 4 + u) * 16 + tx];
        acc[0] += a0[u] * bv; acc[1] += a1[u] * bv;
        acc[2] += a2[u] * bv; acc[3] += a3[u] * bv;
      }
    }
  }

  if (isAB) {
    const int h = ct; const int half = c0 >> 5; const int k = c0 & 31;
    v4f bias = {};
    if (half == 0) bias = *(const v4f*)(b1 + h * 32 + k);
    float* dst = (half == 0) ? Abuf : Bbuf;
#pragma unroll
    for (int i = 0; i < 4; i++) {
      int rg = row0 + r0 + i; int b = rg >> 9; int ir = rg & 511;
      v4f o = (acc[i] + bias) * C2L2E;
      v4f eo = { fexp2(o.x), fexp2(o.y), fexp2(o.z), fexp2(o.w) };
      *(v4f*)(dst + ((b * 4 + h) * 512 + ir) * 32 + k) = eo;
    }
  } else {
    int rg0 = row0 + r0; int b = rg0 >> 9; int ir0 = rg0 & 511;
#pragma unroll
    for (int u = 0; u < 4; u++) {
      int c = ct * 64 + c0 + u;
      v4f o = { acc[0][u], acc[1][u], acc[2][u], acc[3][u] };
      *(v4f*)(xpT + (b * 128 + c) * 512 + ir0) = o;
    }
  }
}

// ---------------------------------------------------------------------------
// adj (fused dist2 + dgf): 16x32 tile, 1x2 micro, grid 2048 = 8 blocks/CU.
// VERBATIM from R14 (57.8 µs build): gram LDS-staged; heads: A global, B LDS;
// e = EA*EB; scalar 4-way rcp-batch; bank-shift swizzle (+rsh).
// ---------------------------------------------------------------------------
__global__ __launch_bounds__(256) void adj_kernel(
    const float* __restrict__ x, const float* __restrict__ sq,
    const float* __restrict__ Abuf, const float* __restrict__ Bbuf,
    const float* __restrict__ W2, const float* __restrict__ b2g,
    float* __restrict__ ADJ)
{
  const int jt = blockIdx.x;   // 0..15 : 32-col tile
  const int it = blockIdx.y;   // 0..31 : 16-row tile
  const int b  = blockIdx.z;
  const int t = threadIdx.x, tx = t & 15, ty = t >> 4;
  const int c0 = 2 * tx;
  __shared__ v4f Bs[2 * 32 * 9];   // [sec][col][slot]
  __shared__ v4f W2s[32];          // baked -2log2e * W2
  __shared__ v2f W2p[32];          // pair sums {w0+w1, w2+w3} of baked values
  __shared__ float hb[4];

  if (t < 32) {
    v4f w = ((const v4f*)W2)[t] * NM2L2E;
    W2s[t] = w;
    v2f p = { w.x + w.y, w.z + w.w };
    W2p[t] = p;
  }
  if (t < 4) {
    float s = b2g[t];
    for (int k = 0; k < 32; k++) s += W2[t * 32 + k];
    hb[t] = s * LOG2E;
  }

  // B staging: 2 v4f per thread per round (sec 0 and 1)
  const int s_col = (t >> 3) & 31, s_k4 = t & 7;
  const int s_slot = (s_k4 + (s_col >> 1) + ((s_col >> 4) << 2)) & 7;

  // read-side slot shift (matches write: col>>1 = tx, col>>4 = tx>>3)
  const int rsh = (tx >> 3) << 2;

  const float* xb = x + (size_t)b * 512 * 128;
  const int irow = it * 16 + ty;
  const float* xi  = xb + irow * 128;          // my single gram row
  const float* xjc = xb + (jt * 32) * 128;     // B-col staging base

  // ---- phase 1: gram (2 rounds x 64k) ----
  v4f gacc0 = {}, gacc1 = {};
  for (int half = 0; half < 2; half++) {
    if (half) __syncthreads();
#pragma unroll
    for (int s = 0; s < 2; s++) {
      Bs[s * 288 + s_col * 9 + s_slot] =
        *(const v4f*)(xjc + s_col * 128 + half * 64 + s * 32 + s_k4 * 4);
    }
    __syncthreads();
#pragma unroll
    for (int sec = 0; sec < 2; sec++) {
#pragma unroll
      for (int k4 = 0; k4 < 8; k4++) {
        v4f a0 = *(const v4f*)(xi + half * 64 + sec * 32 + k4 * 4);
        int sb = (k4 + tx + rsh) & 7;
        v4f b0  = Bs[sec * 288 + (c0 + 0) * 9 + sb];
        v4f b1v = Bs[sec * 288 + (c0 + 1) * 9 + sb];
        gacc0 += a0 * b0; gacc1 += a0 * b1v;
      }
    }
  }
  float si  = sq[b * 512 + irow];
  float sj0 = sq[b * 512 + jt * 32 + c0], sj1 = sq[b * 512 + jt * 32 + c0 + 1];
  float d2L0 = fmaxf(si + sj0 - 2.f * hsum(gacc0), 0.f) * NLOG2E;
  float d2L1 = fmaxf(si + sj1 - 2.f * hsum(gacc1), 0.f) * NLOG2E;

  // ---- phase 2: heads (2 rounds x 2 heads) ----
  float accA0 = 0.f, accA1 = 0.f;
  for (int g = 0; g < 2; g++) {
    __syncthreads();
#pragma unroll
    for (int s = 0; s < 2; s++) {
      Bs[s * 288 + s_col * 9 + s_slot] =
        *(const v4f*)(Bbuf + ((size_t)((b * 4 + g * 2 + s) * 512 + jt * 32 + s_col)) * 32 + s_k4 * 4);
    }
    __syncthreads();
#pragma unroll
    for (int hh = 0; hh < 2; hh++) {
      int h = g * 2 + hh;
      const float* A0 = Abuf + ((size_t)((b * 4 + h) * 512 + irow)) * 32;
      float hbv = hb[h];
      float s0 = hbv, s1 = hbv;                 // log2-domain accumulators
#pragma unroll
      for (int k4 = 0; k4 < 8; k4++) {
        v4f a0 = *(const v4f*)(A0 + k4 * 4);    // EA
        int sb = (k4 + tx + rsh) & 7;
        v4f bv0 = Bs[hh * 288 + (c0 + 0) * 9 + sb];  // EB
        v4f bv1 = Bs[hh * 288 + (c0 + 1) * 9 + sb];
        v4f w  = W2s[h * 8 + k4];               // baked -2log2e*W2
        v2f wp = W2p[h * 8 + k4];               // pair sums
        // ---- col 0 ----
        {
          v4f e = a0 * bv0;                     // e = EA*EB (no exp2)
          float d01 = fmaf(e.x, e.y, e.x + e.y) + 1.f;
          float d23 = fmaf(e.z, e.w, e.z + e.w) + 1.f;
          float n01 = fmaf(w.x, e.y, wp.x); n01 = fmaf(w.y, e.x, n01);
          float n23 = fmaf(w.z, e.w, wp.y); n23 = fmaf(w.w, e.z, n23);
          float num = fmaf(n01, d23, n23 * d01);
          s0 = fmaf(num, frcp(d01 * d23), s0);
        }
        // ---- col 1 ----
        {
          v4f e = a0 * bv1;
          float d01 = fmaf(e.x, e.y, e.x + e.y) + 1.f;
          float d23 = fmaf(e.z, e.w, e.z + e.w) + 1.f;
          float n01 = fmaf(w.x, e.y, wp.x); n01 = fmaf(w.y, e.x, n01);
          float n23 = fmaf(w.z, e.w, wp.y); n23 = fmaf(w.w, e.z, n23);
          float num = fmaf(n01, d23, n23 * d01);
          s1 = fmaf(num, frcp(d01 * d23), s1);
        }
      }
      // epilogue: shared-rcp across the two cols
      float u20 = fexp2(s0), u21 = fexp2(s1);          // e^s (s in log2)
      float sg0 = LN2 * flog2(1.f + u20);              // softplus
      float sg1 = LN2 * flog2(1.f + u21);
      float den0 = fmaf(2.f * sg0, sg0, 1e-6f);
      float den1 = fmaf(2.f * sg1, sg1, 1e-6f);
      float rr = frcp(den0 * den1);
      accA0 += fexp2(d2L0 * (rr * den1));
      accA1 += fexp2(d2L1 * (rr * den0));
    }
  }
  v2f o = { accA0 * 0.25f, accA1 * 0.25f };
  *(v2f*)(ADJ + ((size_t)(b * 512 + irow)) * 512 + jt * 32 + c0) = o;
}

// ---------------------------------------------------------------------------
// out (single kernel, full K=512, bias fused): structural clone of adj's
// gram phase. grid (4,32,4) = 512 blocks = 2/CU, 16x32 output tile, 1x2 micro.
// A = ADJ row from global (broadcast among tx); B = xpT cols LDS-staged.
// ---------------------------------------------------------------------------
__global__ __launch_bounds__(256) void out_kernel(
    const float* __restrict__ ADJ, const float* __restrict__ xpT,
    const float* __restrict__ bp, float* __restrict__ out)
{
  const int ct = blockIdx.x;            // 0..3 : 32-col tile of d=128
  const int it = blockIdx.y;            // 0..31: 16-row tile
  const int b  = blockIdx.z;
  const int t = threadIdx.x, tx = t & 15, ty = t >> 4;
  const int c0 = 2 * tx;
  __shared__ v4f Bs[2 * 32 * 9];
  const int s_col = (t >> 3) & 31, s_k4 = t & 7;
  const int s_slot = (s_k4 + (s_col >> 1) + ((s_col >> 4) << 2)) & 7;
  const int rsh = (tx >> 3) << 2;

  const int irow = it * 16 + ty;
  const float* ai  = ADJ + ((size_t)(b * 512 + irow)) * 512;     // my ADJ row
  const float* xjc = xpT + ((size_t)(b * 128 + ct * 32)) * 512;  // col base

  v4f acc0 = {}, acc1 = {};
  for (int j0 = 0; j0 < 512; j0 += 64) {
    if (j0) __syncthreads();
#pragma unroll
    for (int s = 0; s < 2; s++) {
      Bs[s * 288 + s_col * 9 + s_slot] =
        *(const v4f*)(xjc + s_col * 512 + j0 + s * 32 + s_k4 * 4);
    }
    __syncthreads();
#pragma unroll
    for (int sec = 0; sec < 2; sec++) {
#pragma unroll
      for (int k4 = 0; k4 < 8; k4++) {
        v4f a0 = *(const v4f*)(ai + j0 + sec * 32 + k4 * 4);
        int sb = (k4 + tx + rsh) & 7;
        v4f b0  = Bs[sec * 288 + (c0 + 0) * 9 + sb];
        v4f b1v = Bs[sec * 288 + (c0 + 1) * 9 + sb];
        acc0 += a0 * b0; acc1 += a0 * b1v;
      }
    }
  }
  int c = ct * 32 + c0;
  v2f o = { hsum(acc0) + bp[c], hsum(acc1) + bp[c + 1] };
  *(v2f*)(out + ((size_t)(b * 512 + irow)) * 128 + c) = o;
}

// ---------------------------------------------------------------------------
extern "C" void kernel_launch(void* const* d_in, const int* in_sizes, int n_in,
                              void* d_out, int out_size, void* d_ws, size_t ws_size,
                              hipStream_t stream) {
  const float* x  = (const float*)d_in[0];
  const float* W1 = (const float*)d_in[1];
  const float* b1 = (const float*)d_in[2];
  const float* W2 = (const float*)d_in[3];
  const float* b2 = (const float*)d_in[4];
  const float* Wp = (const float*)d_in[5];
  const float* bp = (const float*)d_in[6];
  float* out = (float*)d_out;

  float* ws  = (float*)d_ws;
  float* sq  = ws;                 // 2048
  float* EA  = ws + 2048;          // 262144
  float* EB  = EA + 262144;        // 262144
  float* xpT = EB + 262144;        // 262144
  float* ADJ = xpT + 262144;       // 1048576

  prep_kernel<<<200, 256, 0, stream>>>(x, W1, b1, Wp, sq, EA, EB, xpT);
  adj_kernel<<<dim3(16, 32, 4), 256, 0, stream>>>(x, sq, EA, EB, W2, b2, ADJ);
  out_kernel<<<dim3(4, 32, 4), 256, 0, stream>>>(ADJ, xpT, bp, out);
}

// Round 16
// 59.417 us; speedup vs baseline: 1.0225x; 1.0225x over previous
//
#include <hip/hip_runtime.h>

typedef float v4f __attribute__((ext_vector_type(4)));
typedef float v2f __attribute__((ext_vector_type(2)));

#define LOG2E   1.4426950408889634f
#define NLOG2E (-1.4426950408889634f)
#define C2L2E   2.8853900817779268f   // 2*log2(e)
#define NM2L2E (-2.8853900817779268f) // -2*log2(e)
#define LN2     0.6931471805599453f

__device__ __forceinline__ float fexp2(float x){ return __builtin_amdgcn_exp2f(x); }
__device__ __forceinline__ float flog2(float x){ return __builtin_amdgcn_logf(x); }
__device__ __forceinline__ float frcp (float x){ return __builtin_amdgcn_rcpf(x); }
__device__ __forceinline__ float hsum(v4f v){ return (v.x+v.y)+(v.z+v.w); }

// ---------------------------------------------------------------------------
// prep (R8-proven, 64-row tiles, 200 blocks):
//   bid 0..127  : EA/EB = exp2((x @ W1half (+b1)) * 2log2e)
//   bid 128..191: xpT = (x @ Wp)^T
//   bid 192..199: sq[row] = ||x_row||^2
// ---------------------------------------------------------------------------
__global__ __launch_bounds__(256) void prep_kernel(
    const float* __restrict__ x, const float* __restrict__ W1,
    const float* __restrict__ b1, const float* __restrict__ Wp,
    float* __restrict__ sq, float* __restrict__ Abuf,
    float* __restrict__ Bbuf, float* __restrict__ xpT)
{
  const int bid = blockIdx.x, t = threadIdx.x;
  if (bid >= 192) {                       // ---- sq ----
    int row = (bid - 192) * 256 + t;      // 0..2047
    const v4f* xv = (const v4f*)(x + row * 128);
    float s = 0.f;
#pragma unroll
    for (int q = 0; q < 32; q++) { v4f v = xv[q]; s += hsum(v * v); }
    sq[row] = s;
    return;
  }
  __shared__ v4f Xs[64 * 9];              // 64 rows x 8 f4, pad 9, slot-swizzled
  __shared__ v4f Ws[32 * 16];             // 32 dd  x 16 f4 (64 cols)
  const bool isAB = bid < 128;
  int it, ct;
  if (isAB) { it = bid >> 2; ct = bid & 3; }
  else      { int q = bid - 128; it = q >> 1; ct = q & 1; }
  const int row0 = it * 64;
  const int tx = t & 15, ty = t >> 4;
  const int r0 = ty * 4, c0 = tx * 4;
  v4f acc[4] = {};                        // acc[i] over 4 cols

  for (int dd0 = 0; dd0 < 128; dd0 += 32) {
    __syncthreads();
#pragma unroll
    for (int s2 = 0; s2 < 2; s2++) {      // stage X (coalesced), swizzled slot
      int idx = t + s2 * 256;
      int row = idx >> 3, k4 = idx & 7;
      v4f v = *(const v4f*)(x + (row0 + row) * 128 + dd0 + k4 * 4);
      Xs[row * 9 + ((k4 + (row >> 2)) & 7)] = v;
    }
#pragma unroll
    for (int s2 = 0; s2 < 2; s2++) {      // stage W (f4 along cols)
      int idx = t + s2 * 256;
      int dd = idx >> 4, cf4 = idx & 15;
      v4f v;
      if (isAB) {
        int cl = cf4 * 4; int half = cl >> 5; int k = cl & 31;
        v = *(const v4f*)(W1 + (ct * 256 + half * 128 + dd0 + dd) * 32 + k);
      } else {
        v = *(const v4f*)(Wp + (dd0 + dd) * 128 + ct * 64 + cf4 * 4);
      }
      Ws[dd * 16 + cf4] = v;
    }
    __syncthreads();
#pragma unroll
    for (int dd4 = 0; dd4 < 8; dd4++) {
      int sa = (dd4 + ty) & 7;
      v4f a0 = Xs[(r0 + 0) * 9 + sa], a1 = Xs[(r0 + 1) * 9 + sa];
      v4f a2 = Xs[(r0 + 2) * 9 + sa], a3 = Xs[(r0 + 3) * 9 + sa];
#pragma unroll
      for (int u = 0; u < 4; u++) {
        v4f bv = Ws[(dd4 * 4 + u) * 16 + tx];
        acc[0] += a0[u] * bv; acc[1] += a1[u] * bv;
        acc[2] += a2[u] * bv; acc[3] += a3[u] * bv;
      }
    }
  }

  if (isAB) {
    const int h = ct; const int half = c0 >> 5; const int k = c0 & 31;
    v4f bias = {};
    if (half == 0) bias = *(const v4f*)(b1 + h * 32 + k);
    float* dst = (half == 0) ? Abuf : Bbuf;
#pragma unroll
    for (int i = 0; i < 4; i++) {
      int rg = row0 + r0 + i; int b = rg >> 9; int ir = rg & 511;
      v4f o = (acc[i] + bias) * C2L2E;
      v4f eo = { fexp2(o.x), fexp2(o.y), fexp2(o.z), fexp2(o.w) };
      *(v4f*)(dst + ((b * 4 + h) * 512 + ir) * 32 + k) = eo;
    }
  } else {
    int rg0 = row0 + r0; int b = rg0 >> 9; int ir0 = rg0 & 511;
#pragma unroll
    for (int u = 0; u < 4; u++) {
      int c = ct * 64 + c0 + u;
      v4f o = { acc[0][u], acc[1][u], acc[2][u], acc[3][u] };
      *(v4f*)(xpT + (b * 128 + c) * 512 + ir0) = o;
    }
  }
}

// ---------------------------------------------------------------------------
// adj (fused dist2 + dgf): 16x32 tile, 1x2 micro, grid 2048 = 8 blocks/CU.
// VERBATIM from R14 (57.8 µs build): gram LDS-staged; heads: A global, B LDS;
// e = EA*EB; scalar 4-way rcp-batch; bank-shift swizzle (+rsh).
// ---------------------------------------------------------------------------
__global__ __launch_bounds__(256) void adj_kernel(
    const float* __restrict__ x, const float* __restrict__ sq,
    const float* __restrict__ Abuf, const float* __restrict__ Bbuf,
    const float* __restrict__ W2, const float* __restrict__ b2g,
    float* __restrict__ ADJ)
{
  const int jt = blockIdx.x;   // 0..15 : 32-col tile
  const int it = blockIdx.y;   // 0..31 : 16-row tile
  const int b  = blockIdx.z;
  const int t = threadIdx.x, tx = t & 15, ty = t >> 4;
  const int c0 = 2 * tx;
  __shared__ v4f Bs[2 * 32 * 9];   // [sec][col][slot]
  __shared__ v4f W2s[32];          // baked -2log2e * W2
  __shared__ v2f W2p[32];          // pair sums {w0+w1, w2+w3} of baked values
  __shared__ float hb[4];

  if (t < 32) {
    v4f w = ((const v4f*)W2)[t] * NM2L2E;
    W2s[t] = w;
    v2f p = { w.x + w.y, w.z + w.w };
    W2p[t] = p;
  }
  if (t < 4) {
    float s = b2g[t];
    for (int k = 0; k < 32; k++) s += W2[t * 32 + k];
    hb[t] = s * LOG2E;
  }

  // B staging: 2 v4f per thread per round (sec 0 and 1)
  const int s_col = (t >> 3) & 31, s_k4 = t & 7;
  const int s_slot = (s_k4 + (s_col >> 1) + ((s_col >> 4) << 2)) & 7;

  // read-side slot shift (matches write: col>>1 = tx, col>>4 = tx>>3)
  const int rsh = (tx >> 3) << 2;

  const float* xb = x + (size_t)b * 512 * 128;
  const int irow = it * 16 + ty;
  const float* xi  = xb + irow * 128;          // my single gram row
  const float* xjc = xb + (jt * 32) * 128;     // B-col staging base

  // ---- phase 1: gram (2 rounds x 64k) ----
  v4f gacc0 = {}, gacc1 = {};
  for (int half = 0; half < 2; half++) {
    if (half) __syncthreads();
#pragma unroll
    for (int s = 0; s < 2; s++) {
      Bs[s * 288 + s_col * 9 + s_slot] =
        *(const v4f*)(xjc + s_col * 128 + half * 64 + s * 32 + s_k4 * 4);
    }
    __syncthreads();
#pragma unroll
    for (int sec = 0; sec < 2; sec++) {
#pragma unroll
      for (int k4 = 0; k4 < 8; k4++) {
        v4f a0 = *(const v4f*)(xi + half * 64 + sec * 32 + k4 * 4);
        int sb = (k4 + tx + rsh) & 7;
        v4f b0  = Bs[sec * 288 + (c0 + 0) * 9 + sb];
        v4f b1v = Bs[sec * 288 + (c0 + 1) * 9 + sb];
        gacc0 += a0 * b0; gacc1 += a0 * b1v;
      }
    }
  }
  float si  = sq[b * 512 + irow];
  float sj0 = sq[b * 512 + jt * 32 + c0], sj1 = sq[b * 512 + jt * 32 + c0 + 1];
  float d2L0 = fmaxf(si + sj0 - 2.f * hsum(gacc0), 0.f) * NLOG2E;
  float d2L1 = fmaxf(si + sj1 - 2.f * hsum(gacc1), 0.f) * NLOG2E;

  // ---- phase 2: heads (2 rounds x 2 heads) ----
  float accA0 = 0.f, accA1 = 0.f;
  for (int g = 0; g < 2; g++) {
    __syncthreads();
#pragma unroll
    for (int s = 0; s < 2; s++) {
      Bs[s * 288 + s_col * 9 + s_slot] =
        *(const v4f*)(Bbuf + ((size_t)((b * 4 + g * 2 + s) * 512 + jt * 32 + s_col)) * 32 + s_k4 * 4);
    }
    __syncthreads();
#pragma unroll
    for (int hh = 0; hh < 2; hh++) {
      int h = g * 2 + hh;
      const float* A0 = Abuf + ((size_t)((b * 4 + h) * 512 + irow)) * 32;
      float hbv = hb[h];
      float s0 = hbv, s1 = hbv;                 // log2-domain accumulators
#pragma unroll
      for (int k4 = 0; k4 < 8; k4++) {
        v4f a0 = *(const v4f*)(A0 + k4 * 4);    // EA
        int sb = (k4 + tx + rsh) & 7;
        v4f bv0 = Bs[hh * 288 + (c0 + 0) * 9 + sb];  // EB
        v4f bv1 = Bs[hh * 288 + (c0 + 1) * 9 + sb];
        v4f w  = W2s[h * 8 + k4];               // baked -2log2e*W2
        v2f wp = W2p[h * 8 + k4];               // pair sums
        // ---- col 0 ----
        {
          v4f e = a0 * bv0;                     // e = EA*EB (no exp2)
          float d01 = fmaf(e.x, e.y, e.x + e.y) + 1.f;
          float d23 = fmaf(e.z, e.w, e.z + e.w) + 1.f;
          float n01 = fmaf(w.x, e.y, wp.x); n01 = fmaf(w.y, e.x, n01);
          float n23 = fmaf(w.z, e.w, wp.y); n23 = fmaf(w.w, e.z, n23);
          float num = fmaf(n01, d23, n23 * d01);
          s0 = fmaf(num, frcp(d01 * d23), s0);
        }
        // ---- col 1 ----
        {
          v4f e = a0 * bv1;
          float d01 = fmaf(e.x, e.y, e.x + e.y) + 1.f;
          float d23 = fmaf(e.z, e.w, e.z + e.w) + 1.f;
          float n01 = fmaf(w.x, e.y, wp.x); n01 = fmaf(w.y, e.x, n01);
          float n23 = fmaf(w.z, e.w, wp.y); n23 = fmaf(w.w, e.z, n23);
          float num = fmaf(n01, d23, n23 * d01);
          s1 = fmaf(num, frcp(d01 * d23), s1);
        }
      }
      // epilogue: shared-rcp across the two cols
      float u20 = fexp2(s0), u21 = fexp2(s1);          // e^s (s in log2)
      float sg0 = LN2 * flog2(1.f + u20);              // softplus
      float sg1 = LN2 * flog2(1.f + u21);
      float den0 = fmaf(2.f * sg0, sg0, 1e-6f);
      float den1 = fmaf(2.f * sg1, sg1, 1e-6f);
      float rr = frcp(den0 * den1);
      accA0 += fexp2(d2L0 * (rr * den1));
      accA1 += fexp2(d2L1 * (rr * den0));
    }
  }
  v2f o = { accA0 * 0.25f, accA1 * 0.25f };
  *(v2f*)(ADJ + ((size_t)(b * 512 + irow)) * 512 + jt * 32 + c0) = o;
}

// ---------------------------------------------------------------------------
// out_gemm: part[ks] = ADJ[:, kslice] @ xpT[:, kslice]^T  (K=512 split by 4)
// grid (4,16,16) = 1024 blocks = 4/CU.  CHANGE vs R14: ADJ rows read directly
// from global (2 fixed rows/thread, 16-lane broadcast) — Ajs LDS staging
// dropped; Xps staging keeps the bank-shift swizzle.
// ---------------------------------------------------------------------------
__global__ __launch_bounds__(256) void out_gemm(
    const float* __restrict__ ADJ, const float* __restrict__ xpT,
    float* __restrict__ part)
{
  const int ct = blockIdx.x;            // 0..3 : 32-col tile
  const int it = blockIdx.y;            // 0..15: 32-row tile
  const int z = blockIdx.z; const int b = z >> 2, ks = z & 3;
  const int t = threadIdx.x, tx = t & 15, ty = t >> 4;
  const int r0 = 2 * ty, c0 = 2 * tx;
  __shared__ v4f Xps[32 * 9];
  v4f acc[4] = {};
  const int row = t >> 3, k4l = t & 7;
  const int slot = (k4l + (row >> 1) + ((row >> 4) << 2)) & 7;
  const int rsh = (tx >> 3) << 2;

  const float* a0p = ADJ + ((size_t)(b * 512 + it * 32 + r0)) * 512;
  const float* a1p = a0p + 512;

  for (int k0 = ks * 128; k0 < ks * 128 + 128; k0 += 32) {
    __syncthreads();
    Xps[row * 9 + slot] =
      *(const v4f*)(xpT + ((size_t)(b * 128 + ct * 32 + row)) * 512 + k0 + k4l * 4);
    __syncthreads();
#pragma unroll
    for (int k4 = 0; k4 < 8; k4++) {
      v4f a0 = *(const v4f*)(a0p + k0 + k4 * 4);   // broadcast among tx
      v4f a1 = *(const v4f*)(a1p + k0 + k4 * 4);
      int sb = (k4 + tx + rsh) & 7;
      v4f b0 = Xps[(c0 + 0) * 9 + sb], b1v = Xps[(c0 + 1) * 9 + sb];
      acc[0] += a0 * b0; acc[1] += a0 * b1v;
      acc[2] += a1 * b0; acc[3] += a1 * b1v;
    }
  }
  float* dst = part + ((size_t)((ks * 4 + b) * 512 + it * 32 + r0)) * 128 + ct * 32 + c0;
  v2f o0 = { hsum(acc[0]), hsum(acc[1]) };
  v2f o1 = { hsum(acc[2]), hsum(acc[3]) };
  *(v2f*)dst = o0;
  *(v2f*)(dst + 128) = o1;
}

__global__ __launch_bounds__(256) void reduce_out(
    const float* __restrict__ part, const float* __restrict__ bp,
    float* __restrict__ out)
{
  int g = blockIdx.x * 256 + threadIdx.x;   // v4f index, 65536 total
  const v4f* p = (const v4f*)part;
  v4f s = (p[g] + p[g + 65536]) + (p[g + 131072] + p[g + 196608]);
  v4f bv = ((const v4f*)bp)[g & 31];
  ((v4f*)out)[g] = s + bv;
}

// ---------------------------------------------------------------------------
extern "C" void kernel_launch(void* const* d_in, const int* in_sizes, int n_in,
                              void* d_out, int out_size, void* d_ws, size_t ws_size,
                              hipStream_t stream) {
  const float* x  = (const float*)d_in[0];
  const float* W1 = (const float*)d_in[1];
  const float* b1 = (const float*)d_in[2];
  const float* W2 = (const float*)d_in[3];
  const float* b2 = (const float*)d_in[4];
  const float* Wp = (const float*)d_in[5];
  const float* bp = (const float*)d_in[6];
  float* out = (float*)d_out;

  float* ws  = (float*)d_ws;
  float* sq  = ws;                 // 2048
  float* EA  = ws + 2048;          // 262144
  float* EB  = EA + 262144;        // 262144
  float* xpT = EB + 262144;        // 262144
  float* ADJ = xpT + 262144;       // 1048576
  float* part = ADJ + 1048576;     // 1048576

  prep_kernel<<<200, 256, 0, stream>>>(x, W1, b1, Wp, sq, EA, EB, xpT);
  adj_kernel<<<dim3(16, 32, 4), 256, 0, stream>>>(x, sq, EA, EB, W2, b2, ADJ);
  out_gemm<<<dim3(4, 16, 16), 256, 0, stream>>>(ADJ, xpT, part);
  reduce_out<<<256, 256, 0, stream>>>(part, bp, out);
}

// Round 17
// 57.638 us; speedup vs baseline: 1.0541x; 1.0309x over previous
//
#include <hip/hip_runtime.h>

typedef float v4f __attribute__((ext_vector_type(4)));
typedef float v2f __attribute__((ext_vector_type(2)));

#define LOG2E   1.4426950408889634f
#define NLOG2E (-1.4426950408889634f)
#define C2L2E   2.8853900817779268f   // 2*log2(e)
#define NM2L2E (-2.8853900817779268f) // -2*log2(e)
#define LN2     0.6931471805599453f

__device__ __forceinline__ float fexp2(float x){ return __builtin_amdgcn_exp2f(x); }
__device__ __forceinline__ float flog2(float x){ return __builtin_amdgcn_logf(x); }
__device__ __forceinline__ float frcp (float x){ return __builtin_amdgcn_rcpf(x); }
__device__ __forceinline__ float hsum(v4f v){ return (v.x+v.y)+(v.z+v.w); }

// ---------------------------------------------------------------------------
// prep (R8-proven, 64-row tiles, 200 blocks):
//   bid 0..127  : EA/EB = exp2((x @ W1half (+b1)) * 2log2e)
//   bid 128..191: xpT = (x @ Wp)^T
//   bid 192..199: sq[row] = ||x_row||^2
// ---------------------------------------------------------------------------
__global__ __launch_bounds__(256) void prep_kernel(
    const float* __restrict__ x, const float* __restrict__ W1,
    const float* __restrict__ b1, const float* __restrict__ Wp,
    float* __restrict__ sq, float* __restrict__ Abuf,
    float* __restrict__ Bbuf, float* __restrict__ xpT)
{
  const int bid = blockIdx.x, t = threadIdx.x;
  if (bid >= 192) {                       // ---- sq ----
    int row = (bid - 192) * 256 + t;      // 0..2047
    const v4f* xv = (const v4f*)(x + row * 128);
    float s = 0.f;
#pragma unroll
    for (int q = 0; q < 32; q++) { v4f v = xv[q]; s += hsum(v * v); }
    sq[row] = s;
    return;
  }
  __shared__ v4f Xs[64 * 9];              // 64 rows x 8 f4, pad 9, slot-swizzled
  __shared__ v4f Ws[32 * 16];             // 32 dd  x 16 f4 (64 cols)
  const bool isAB = bid < 128;
  int it, ct;
  if (isAB) { it = bid >> 2; ct = bid & 3; }
  else      { int q = bid - 128; it = q >> 1; ct = q & 1; }
  const int row0 = it * 64;
  const int tx = t & 15, ty = t >> 4;
  const int r0 = ty * 4, c0 = tx * 4;
  v4f acc[4] = {};                        // acc[i] over 4 cols

  for (int dd0 = 0; dd0 < 128; dd0 += 32) {
    __syncthreads();
#pragma unroll
    for (int s2 = 0; s2 < 2; s2++) {      // stage X (coalesced), swizzled slot
      int idx = t + s2 * 256;
      int row = idx >> 3, k4 = idx & 7;
      v4f v = *(const v4f*)(x + (row0 + row) * 128 + dd0 + k4 * 4);
      Xs[row * 9 + ((k4 + (row >> 2)) & 7)] = v;
    }
#pragma unroll
    for (int s2 = 0; s2 < 2; s2++) {      // stage W (f4 along cols)
      int idx = t + s2 * 256;
      int dd = idx >> 4, cf4 = idx & 15;
      v4f v;
      if (isAB) {
        int cl = cf4 * 4; int half = cl >> 5; int k = cl & 31;
        v = *(const v4f*)(W1 + (ct * 256 + half * 128 + dd0 + dd) * 32 + k);
      } else {
        v = *(const v4f*)(Wp + (dd0 + dd) * 128 + ct * 64 + cf4 * 4);
      }
      Ws[dd * 16 + cf4] = v;
    }
    __syncthreads();
#pragma unroll
    for (int dd4 = 0; dd4 < 8; dd4++) {
      int sa = (dd4 + ty) & 7;
      v4f a0 = Xs[(r0 + 0) * 9 + sa], a1 = Xs[(r0 + 1) * 9 + sa];
      v4f a2 = Xs[(r0 + 2) * 9 + sa], a3 = Xs[(r0 + 3) * 9 + sa];
#pragma unroll
      for (int u = 0; u < 4; u++) {
        v4f bv = Ws[(dd4 * 4 + u) * 16 + tx];
        acc[0] += a0[u] * bv; acc[1] += a1[u] * bv;
        acc[2] += a2[u] * bv; acc[3] += a3[u] * bv;
      }
    }
  }

  if (isAB) {
    const int h = ct; const int half = c0 >> 5; const int k = c0 & 31;
    v4f bias = {};
    if (half == 0) bias = *(const v4f*)(b1 + h * 32 + k);
    float* dst = (half == 0) ? Abuf : Bbuf;
#pragma unroll
    for (int i = 0; i < 4; i++) {
      int rg = row0 + r0 + i; int b = rg >> 9; int ir = rg & 511;
      v4f o = (acc[i] + bias) * C2L2E;
      v4f eo = { fexp2(o.x), fexp2(o.y), fexp2(o.z), fexp2(o.w) };
      *(v4f*)(dst + ((b * 4 + h) * 512 + ir) * 32 + k) = eo;
    }
  } else {
    int rg0 = row0 + r0; int b = rg0 >> 9; int ir0 = rg0 & 511;
#pragma unroll
    for (int u = 0; u < 4; u++) {
      int c = ct * 64 + c0 + u;
      v4f o = { acc[0][u], acc[1][u], acc[2][u], acc[3][u] };
      *(v4f*)(xpT + (b * 128 + c) * 512 + ir0) = o;
    }
  }
}

// ---------------------------------------------------------------------------
// adj (fused dist2 + dgf): 16x32 tile, 1x2 micro, grid 2048 = 8 blocks/CU.
// VERBATIM R14 (57.8 µs build): gram LDS-staged; heads: A global, B LDS;
// e = EA*EB; scalar 4-way rcp-batch; bank-shift swizzle (+rsh).
// ---------------------------------------------------------------------------
__global__ __launch_bounds__(256) void adj_kernel(
    const float* __restrict__ x, const float* __restrict__ sq,
    const float* __restrict__ Abuf, const float* __restrict__ Bbuf,
    const float* __restrict__ W2, const float* __restrict__ b2g,
    float* __restrict__ ADJ)
{
  const int jt = blockIdx.x;   // 0..15 : 32-col tile
  const int it = blockIdx.y;   // 0..31 : 16-row tile
  const int b  = blockIdx.z;
  const int t = threadIdx.x, tx = t & 15, ty = t >> 4;
  const int c0 = 2 * tx;
  __shared__ v4f Bs[2 * 32 * 9];   // [sec][col][slot]
  __shared__ v4f W2s[32];          // baked -2log2e * W2
  __shared__ v2f W2p[32];          // pair sums {w0+w1, w2+w3} of baked values
  __shared__ float hb[4];

  if (t < 32) {
    v4f w = ((const v4f*)W2)[t] * NM2L2E;
    W2s[t] = w;
    v2f p = { w.x + w.y, w.z + w.w };
    W2p[t] = p;
  }
  if (t < 4) {
    float s = b2g[t];
    for (int k = 0; k < 32; k++) s += W2[t * 32 + k];
    hb[t] = s * LOG2E;
  }

  // B staging: 2 v4f per thread per round (sec 0 and 1)
  const int s_col = (t >> 3) & 31, s_k4 = t & 7;
  const int s_slot = (s_k4 + (s_col >> 1) + ((s_col >> 4) << 2)) & 7;

  // read-side slot shift (matches write: col>>1 = tx, col>>4 = tx>>3)
  const int rsh = (tx >> 3) << 2;

  const float* xb = x + (size_t)b * 512 * 128;
  const int irow = it * 16 + ty;
  const float* xi  = xb + irow * 128;          // my single gram row
  const float* xjc = xb + (jt * 32) * 128;     // B-col staging base

  // ---- phase 1: gram (2 rounds x 64k) ----
  v4f gacc0 = {}, gacc1 = {};
  for (int half = 0; half < 2; half++) {
    if (half) __syncthreads();
#pragma unroll
    for (int s = 0; s < 2; s++) {
      Bs[s * 288 + s_col * 9 + s_slot] =
        *(const v4f*)(xjc + s_col * 128 + half * 64 + s * 32 + s_k4 * 4);
    }
    __syncthreads();
#pragma unroll
    for (int sec = 0; sec < 2; sec++) {
#pragma unroll
      for (int k4 = 0; k4 < 8; k4++) {
        v4f a0 = *(const v4f*)(xi + half * 64 + sec * 32 + k4 * 4);
        int sb = (k4 + tx + rsh) & 7;
        v4f b0  = Bs[sec * 288 + (c0 + 0) * 9 + sb];
        v4f b1v = Bs[sec * 288 + (c0 + 1) * 9 + sb];
        gacc0 += a0 * b0; gacc1 += a0 * b1v;
      }
    }
  }
  float si  = sq[b * 512 + irow];
  float sj0 = sq[b * 512 + jt * 32 + c0], sj1 = sq[b * 512 + jt * 32 + c0 + 1];
  float d2L0 = fmaxf(si + sj0 - 2.f * hsum(gacc0), 0.f) * NLOG2E;
  float d2L1 = fmaxf(si + sj1 - 2.f * hsum(gacc1), 0.f) * NLOG2E;

  // ---- phase 2: heads (2 rounds x 2 heads) ----
  float accA0 = 0.f, accA1 = 0.f;
  for (int g = 0; g < 2; g++) {
    __syncthreads();
#pragma unroll
    for (int s = 0; s < 2; s++) {
      Bs[s * 288 + s_col * 9 + s_slot] =
        *(const v4f*)(Bbuf + ((size_t)((b * 4 + g * 2 + s) * 512 + jt * 32 + s_col)) * 32 + s_k4 * 4);
    }
    __syncthreads();
#pragma unroll
    for (int hh = 0; hh < 2; hh++) {
      int h = g * 2 + hh;
      const float* A0 = Abuf + ((size_t)((b * 4 + h) * 512 + irow)) * 32;
      float hbv = hb[h];
      float s0 = hbv, s1 = hbv;                 // log2-domain accumulators
#pragma unroll
      for (int k4 = 0; k4 < 8; k4++) {
        v4f a0 = *(const v4f*)(A0 + k4 * 4);    // EA
        int sb = (k4 + tx + rsh) & 7;
        v4f bv0 = Bs[hh * 288 + (c0 + 0) * 9 + sb];  // EB
        v4f bv1 = Bs[hh * 288 + (c0 + 1) * 9 + sb];
        v4f w  = W2s[h * 8 + k4];               // baked -2log2e*W2
        v2f wp = W2p[h * 8 + k4];               // pair sums
        // ---- col 0 ----
        {
          v4f e = a0 * bv0;                     // e = EA*EB (no exp2)
          float d01 = fmaf(e.x, e.y, e.x + e.y) + 1.f;
          float d23 = fmaf(e.z, e.w, e.z + e.w) + 1.f;
          float n01 = fmaf(w.x, e.y, wp.x); n01 = fmaf(w.y, e.x, n01);
          float n23 = fmaf(w.z, e.w, wp.y); n23 = fmaf(w.w, e.z, n23);
          float num = fmaf(n01, d23, n23 * d01);
          s0 = fmaf(num, frcp(d01 * d23), s0);
        }
        // ---- col 1 ----
        {
          v4f e = a0 * bv1;
          float d01 = fmaf(e.x, e.y, e.x + e.y) + 1.f;
          float d23 = fmaf(e.z, e.w, e.z + e.w) + 1.f;
          float n01 = fmaf(w.x, e.y, wp.x); n01 = fmaf(w.y, e.x, n01);
          float n23 = fmaf(w.z, e.w, wp.y); n23 = fmaf(w.w, e.z, n23);
          float num = fmaf(n01, d23, n23 * d01);
          s1 = fmaf(num, frcp(d01 * d23), s1);
        }
      }
      // epilogue: shared-rcp across the two cols
      float u20 = fexp2(s0), u21 = fexp2(s1);          // e^s (s in log2)
      float sg0 = LN2 * flog2(1.f + u20);              // softplus
      float sg1 = LN2 * flog2(1.f + u21);
      float den0 = fmaf(2.f * sg0, sg0, 1e-6f);
      float den1 = fmaf(2.f * sg1, sg1, 1e-6f);
      float rr = frcp(den0 * den1);
      accA0 += fexp2(d2L0 * (rr * den1));
      accA1 += fexp2(d2L1 * (rr * den0));
    }
  }
  v2f o = { accA0 * 0.25f, accA1 * 0.25f };
  *(v2f*)(ADJ + ((size_t)(b * 512 + irow)) * 512 + jt * 32 + c0) = o;
}

// ---------------------------------------------------------------------------
// out_gemm: part[ks] = ADJ[:, kslice] @ xpT[:, kslice]^T  (K=512 split by 4)
// grid (4,16,16) = 1024 blocks = 4/CU.  (R14 version: both operands LDS.)
// ---------------------------------------------------------------------------
__global__ __launch_bounds__(256) void out_gemm(
    const float* __restrict__ ADJ, const float* __restrict__ xpT,
    float* __restrict__ part)
{
  const int ct = blockIdx.x;            // 0..3 : 32-col tile
  const int it = blockIdx.y;            // 0..15: 32-row tile
  const int z = blockIdx.z; const int b = z >> 2, ks = z & 3;
  const int t = threadIdx.x, tx = t & 15, ty = t >> 4;
  const int r0 = 2 * ty, c0 = 2 * tx;
  __shared__ v4f Ajs[32 * 9], Xps[32 * 9];
  v4f acc[4] = {};
  const int row = t >> 3, k4l = t & 7, slot = (k4l + (row >> 1)) & 7;

  for (int k0 = ks * 128; k0 < ks * 128 + 128; k0 += 32) {
    __syncthreads();
    Ajs[row * 9 + slot] = *(const v4f*)(ADJ + ((size_t)(b * 512 + it * 32 + row)) * 512 + k0 + k4l * 4);
    Xps[row * 9 + slot] = *(const v4f*)(xpT + ((size_t)(b * 128 + ct * 32 + row)) * 512 + k0 + k4l * 4);
    __syncthreads();
#pragma unroll
    for (int k4 = 0; k4 < 8; k4++) {
      int sa = (k4 + ty) & 7, sb = (k4 + tx) & 7;
      v4f a0 = Ajs[(r0 + 0) * 9 + sa], a1 = Ajs[(r0 + 1) * 9 + sa];
      v4f b0 = Xps[(c0 + 0) * 9 + sb], b1v = Xps[(c0 + 1) * 9 + sb];
      acc[0] += a0 * b0; acc[1] += a0 * b1v;
      acc[2] += a1 * b0; acc[3] += a1 * b1v;
    }
  }
  float* dst = part + ((size_t)((ks * 4 + b) * 512 + it * 32 + r0)) * 128 + ct * 32 + c0;
  v2f o0 = { hsum(acc[0]), hsum(acc[1]) };
  v2f o1 = { hsum(acc[2]), hsum(acc[3]) };
  *(v2f*)dst = o0;
  *(v2f*)(dst + 128) = o1;
}

__global__ __launch_bounds__(256) void reduce_out(
    const float* __restrict__ part, const float* __restrict__ bp,
    float* __restrict__ out)
{
  int g = blockIdx.x * 256 + threadIdx.x;   // v4f index, 65536 total
  const v4f* p = (const v4f*)part;
  v4f s = (p[g] + p[g + 65536]) + (p[g + 131072] + p[g + 196608]);
  v4f bv = ((const v4f*)bp)[g & 31];
  ((v4f*)out)[g] = s + bv;
}

// ---------------------------------------------------------------------------
extern "C" void kernel_launch(void* const* d_in, const int* in_sizes, int n_in,
                              void* d_out, int out_size, void* d_ws, size_t ws_size,
                              hipStream_t stream) {
  const float* x  = (const float*)d_in[0];
  const float* W1 = (const float*)d_in[1];
  const float* b1 = (const float*)d_in[2];
  const float* W2 = (const float*)d_in[3];
  const float* b2 = (const float*)d_in[4];
  const float* Wp = (const float*)d_in[5];
  const float* bp = (const float*)d_in[6];
  float* out = (float*)d_out;

  float* ws  = (float*)d_ws;
  float* sq  = ws;                 // 2048
  float* EA  = ws + 2048;          // 262144
  float* EB  = EA + 262144;        // 262144
  float* xpT = EB + 262144;        // 262144
  float* ADJ = xpT + 262144;       // 1048576
  float* part = ADJ + 1048576;     // 1048576

  prep_kernel<<<200, 256, 0, stream>>>(x, W1, b1, Wp, sq, EA, EB, xpT);
  adj_kernel<<<dim3(16, 32, 4), 256, 0, stream>>>(x, sq, EA, EB, W2, b2, ADJ);
  out_gemm<<<dim3(4, 16, 16), 256, 0, stream>>>(ADJ, xpT, part);
  reduce_out<<<256, 256, 0, stream>>>(part, bp, out);
}